// Round 15
// baseline (427.555 us; speedup 1.0000x reference)
//
#include <hip/hip_runtime.h>

// SchNet on MI355X — round 15: latency attack on k_layer. Nearest-neighbor
// table (TROWS 4096, no lerp), 8-edge unroll (16 outstanding loads),
// interleaved update/coordagg blocks (b%3), packed (pos,dc) float4 for
// coordagg, k_sumpref unroll, merged scan. Structure = round 14 (race-free).

#define NN 10000
#define EE 320000
#define HH 128
#define GG 50
#define NF 128
#define NL 6
#define TROWS 4096
#define NB 128          // histogram blocks; EE/NB = 2500 edges each (fits u16)

typedef unsigned short u16;
typedef unsigned int u32;
typedef short bf16x8 __attribute__((ext_vector_type(8)));
typedef float f32x4  __attribute__((ext_vector_type(4)));

__device__ __forceinline__ float us2f(u16 u){
  union { float f; u32 i; } v; v.i = ((u32)u) << 16; return v.f;
}
__device__ __forceinline__ u16 f2us(float x){
  union { float f; u32 i; } v; v.f = x;
  u32 r = v.i + 0x7fffu + ((v.i >> 16) & 1u);   // RNE
  return (u16)(r >> 16);
}
__device__ __forceinline__ float ldin(const void* p, int i, int bf){
  return bf ? us2f(((const u16*)p)[i]) : ((const float*)p)[i];
}
__device__ __forceinline__ float sspf(float x){
  return fmaxf(x, 0.f) + __logf(1.f + __expf(-fabsf(x))) - 0.6931472f;
}
__device__ __forceinline__ int detect_bf(const u32* __restrict__ zraw){
  int lane = threadIdx.x & 63;
  int c = 0;
  #pragma unroll
  for(int j=0;j<4;j++){
    u32 w = zraw[lane*4+j];
    u32 hb = (w >> 8) & 0x7F;
    c += (hb >= 0x38 && hb <= 0x41) ? 1 : 0;
  }
  return __popcll(__ballot(c >= 2)) >= 32;
}
__device__ __forceinline__ int detect_i64(const int* __restrict__ ei_raw){
  int lane = threadIdx.x & 63;
  int c = 0;
  #pragma unroll
  for(int j=0;j<4;j++) c += (ei_raw[2*(lane*4+j)+1] == 0) ? 1 : 0;
  return __popcll(__ballot(c >= 3)) >= 32;
}

// ---------- K1: fused init + weight prep ----------
__global__ void k_prep(const u32* __restrict__ zraw, const void* __restrict__ pos_in,
    const void* __restrict__ mlp1_w, const void* __restrict__ mlp1_b,
    const void* __restrict__ mlp2_w, const void* __restrict__ mlp2_b,
    const void* __restrict__ lin1_w, const void* __restrict__ lin2_w,
    const void* __restrict__ lin2_b, const void* __restrict__ lin_w,
    const void* __restrict__ lin_b,  const void* __restrict__ coord_w,
    const void* __restrict__ coord_b,
    float* __restrict__ h, float* __restrict__ pc40, int* __restrict__ wmaxi,
    float* __restrict__ b1f, float* __restrict__ b2v,
    float* __restrict__ w1t, float* __restrict__ w2t,
    float* __restrict__ l1t, u16* __restrict__ l1b, u16* __restrict__ l2b,
    float* __restrict__ l2bf, u16* __restrict__ lwb,
    float* __restrict__ lbf, float* __restrict__ cwf, float* __restrict__ cbf)
{
  int bf = detect_bf(zraw);
  int b = blockIdx.x;
  if(b < NN*HH/256){
    int i = b*256 + threadIdx.x;
    h[i] = ldin(zraw, i, bf);
    if(i < NN*3){
      int n = i/3, comp = i%3;
      pc40[n*4 + comp] = ldin(pos_in, i, bf);
    }
    if(i == 0) *wmaxi = 0;
  } else {
    int i = (b - NN*HH/256)*256 + threadIdx.x;    // < NL*NF*NF
    if(i < NL*NF){
      b1f[i]  = ldin(mlp1_b, i, bf);
      b2v[i]  = ldin(mlp2_b, i, bf);
      l2bf[i] = ldin(lin2_b, i, bf);
      lbf[i]  = ldin(lin_b,  i, bf);
    }
    if(i < NL*GG*NF){                             // w1t[l][g][f]
      int l = i/(GG*NF), rem = i%(GG*NF);
      int g = rem/NF, f = rem%NF;
      w1t[i] = ldin(mlp1_w, (l*NF + f)*GG + g, bf);
    }
    if(i < NL*NF*NF){
      int l = i/(NF*NF), rem = i%(NF*NF);
      int k = rem/NF, f = rem%NF;
      w2t[i] = ldin(mlp2_w, l*NF*NF + f*NF + k, bf);
      l1t[i] = ldin(lin1_w, l*NF*HH + f*HH + k, bf);
      l1b[i] = f2us(ldin(lin1_w, i, bf));         // row-major bf16 (MFMA B)
      l2b[i] = f2us(ldin(lin2_w, i, bf));
      lwb[i] = f2us(ldin(lin_w,  i, bf));
    }
    if(i < NL*(GG+2*HH)) cwf[i] = ldin(coord_w, i, bf);
    if(i < NL) cbf[i] = ldin(coord_b, i, bf);
  }
}

// ---------- K2: decode ei, distances (pc4 float4), LDS histograms ----------
__global__ void k_count(const int* __restrict__ ei_raw, const float* __restrict__ pc4,
                        int* __restrict__ eiN, float* __restrict__ wE,
                        u32* __restrict__ partR32, u32* __restrict__ partC32,
                        int* __restrict__ wmaxi){
  __shared__ u32 hr[NN/2];
  __shared__ u32 hc[NN/2];
  int is64 = detect_i64(ei_raw);
  int b = blockIdx.x, tid = threadIdx.x;          // grid: NB x 256
  for(int i=tid; i<NN/2; i+=256){ hr[i]=0; hc[i]=0; }
  __syncthreads();
  int e0 = b*(EE/NB), e1 = e0 + EE/NB;
  float wm = 0.f;
  for(int e = e0 + tid; e < e1; e += 256){
    int r = is64 ? ei_raw[2*e] : ei_raw[e];
    int c = is64 ? ei_raw[2*(EE+e)] : ei_raw[EE+e];
    eiN[e] = r; eiN[EE+e] = c;
    float4 pr = *(const float4*)&pc4[r*4];
    float4 pcv = *(const float4*)&pc4[c*4];
    float dx = pr.x-pcv.x, dy = pr.y-pcv.y, dz = pr.z-pcv.z;
    float w = sqrtf(dx*dx + dy*dy + dz*dz);
    wE[e] = w;
    wm = fmaxf(wm, w);
    atomicAdd(&hr[r>>1], (r&1) ? 0x10000u : 1u);
    atomicAdd(&hc[c>>1], (c&1) ? 0x10000u : 1u);
  }
  #pragma unroll
  for(int s=32; s>0; s>>=1) wm = fmaxf(wm, __shfl_down(wm, s, 64));
  if((tid & 63) == 0) atomicMax(wmaxi, __float_as_int(wm));
  __syncthreads();
  for(int i=tid; i<NN/2; i+=256){
    partR32[(size_t)b*(NN/2) + i] = hr[i];
    partC32[(size_t)b*(NN/2) + i] = hc[i];
  }
}

// ---------- K3: u16 partials -> exclusive block-prefixes + totals (unroll 8) ----------
__global__ void k_sumpref(u16* __restrict__ partR16, u16* __restrict__ partC16,
                          int* __restrict__ degR, int* __restrict__ degC){
  int n = blockIdx.x*256 + threadIdx.x;
  if(n >= NN) return;
  u32 rr = 0, rc = 0;
  for(int b0=0; b0<NB; b0+=8){
    u32 vr[8], vc[8];
    #pragma unroll
    for(int j=0;j<8;j++){
      vr[j] = partR16[(size_t)(b0+j)*NN + n];
      vc[j] = partC16[(size_t)(b0+j)*NN + n];
    }
    #pragma unroll
    for(int j=0;j<8;j++){
      partR16[(size_t)(b0+j)*NN + n] = (u16)rr; rr += vr[j];
      partC16[(size_t)(b0+j)*NN + n] = (u16)rc; rc += vc[j];
    }
  }
  degR[n] = (int)rr; degC[n] = (int)rc;
}

// ---------- K4: merged dual exclusive scan ----------
__global__ void k_scan2(const int* __restrict__ col_deg, const int* __restrict__ deg_row,
                        int* __restrict__ col_start, int* __restrict__ row_start){
  __shared__ int pc[1024];
  __shared__ int pr[1024];
  int tid = threadIdx.x;
  const int CH = (NN + 1023)/1024;
  int base = tid*CH;
  int sc = 0, sr = 0;
  for(int i=0;i<CH;i++){
    int idx = base+i;
    if(idx<NN){ sc += col_deg[idx]; sr += deg_row[idx]; }
  }
  pc[tid] = sc; pr[tid] = sr;
  __syncthreads();
  for(int off=1; off<1024; off<<=1){
    int vc = (tid>=off) ? pc[tid-off] : 0;
    int vr = (tid>=off) ? pr[tid-off] : 0;
    __syncthreads();
    pc[tid] += vc; pr[tid] += vr;
    __syncthreads();
  }
  int runc = (tid==0) ? 0 : pc[tid-1];
  int runr = (tid==0) ? 0 : pr[tid-1];
  for(int i=0;i<CH;i++){
    int idx = base+i;
    if(idx<NN){
      col_start[idx]=runc; runc += col_deg[idx];
      row_start[idx]=runr; runr += deg_row[idx];
    }
  }
  if(tid==1023){ col_start[NN] = runc; row_start[NN] = runr; }
}

// ---------- K5a: CSR fill via LDS rank histograms ----------
__global__ void k_fill(const int* __restrict__ eiN, const float* __restrict__ wE,
                       const int* __restrict__ col_start, const int* __restrict__ row_start,
                       const u16* __restrict__ partR16, const u16* __restrict__ partC16,
                       int* __restrict__ row_s, float* __restrict__ wEs,
                       int* __restrict__ rcol_s, float* __restrict__ rw_s){
  __shared__ u32 hr[NN/2];
  __shared__ u32 hc[NN/2];
  int b = blockIdx.x, t = threadIdx.x;
  for(int i=t; i<NN/2; i+=256){ hr[i]=0; hc[i]=0; }
  __syncthreads();
  int e0 = b*(EE/NB), e1 = e0 + EE/NB;
  for(int e = e0 + t; e < e1; e += 256){
    int r = eiN[e], c = eiN[EE+e];
    float w = wE[e];
    u32 oldc = atomicAdd(&hc[c>>1], (c&1) ? 0x10000u : 1u);
    u32 rkc = (c&1) ? (oldc >> 16) : (oldc & 0xFFFFu);
    int p = col_start[c] + (int)partC16[(size_t)b*NN + c] + (int)rkc;
    row_s[p] = r; wEs[p] = w;
    u32 oldr = atomicAdd(&hr[r>>1], (r&1) ? 0x10000u : 1u);
    u32 rkr = (r&1) ? (oldr >> 16) : (oldr & 0xFFFFu);
    int p2 = row_start[r] + (int)partR16[(size_t)b*NN + r] + (int)rkr;
    rcol_s[p2] = c; rw_s[p2] = w;
  }
}

// ---------- K5b: table build (bf16, per-row, nearest-lookup) + layer-0 node ----------
__global__ void k_tabnode(const float* __restrict__ w1t, const float* __restrict__ b1f,
                          const float* __restrict__ w2t, const float* __restrict__ b2v,
                          const float* __restrict__ cwf, const int* __restrict__ wmaxi,
                          u16* __restrict__ tabB, float* __restrict__ tabS,
                          const float* __restrict__ h, const float* __restrict__ l1t,
                          u16* __restrict__ xfb0, float* __restrict__ dr0,
                          float* __restrict__ pc40){
  __shared__ float attr[16*64];                   // 4 KB
  __shared__ float tls[128*17];                   // 8.5 KB
  int b = blockIdx.x, t = threadIdx.x;
  if(b < NL*256){
    int l = b >> 8;
    int r0 = (b & 255)*16;
    int f = t & 127, half = t >> 7;
    float delta = __int_as_float(*wmaxi) / (float)(TROWS-1);
    for(int idx=t; idx<16*64; idx+=256){
      int r = idx >> 6, g = idx & 63;
      float w = (float)(r0 + r)*delta;
      float d = w - (float)g*(10.f/49.f);
      attr[idx] = (g < GG) ? __expf(-12.005f*d*d) : 0.f;
    }
    __syncthreads();
    const float* __restrict__ w1 = w1t + l*GG*NF;
    float b1 = b1f[l*NF + f];
    float a1[8];
    #pragma unroll
    for(int r=0;r<8;r++) a1[r] = b1;
    for(int g=0; g<GG; g++){
      float wv = w1[g*NF + f];
      #pragma unroll
      for(int r=0;r<8;r++) a1[r] += attr[(half*8 + r)*64 + g]*wv;
    }
    #pragma unroll
    for(int r=0;r<8;r++) tls[f*17 + half*8 + r] = sspf(a1[r]);
    __syncthreads();
    const float* __restrict__ w2 = w2t + l*NF*NF;
    float b2 = b2v[l*NF + f];
    float a2[8];
    #pragma unroll
    for(int r=0;r<8;r++) a2[r] = b2;
    for(int k=0;k<NF;k++){
      float wv = w2[k*NF + f];
      #pragma unroll
      for(int r=0;r<8;r++) a2[r] += tls[k*17 + half*8 + r]*wv;
    }
    #pragma unroll
    for(int r=0;r<8;r++){
      int row = r0 + half*8 + r;
      float w = (float)row*delta;
      float C = 0.5f*(cosf(w*0.3141592653589793f) + 1.f);
      tabB[((size_t)l*TROWS + row)*NF + f] = f2us(a2[r]*C);
    }
    if(t < 16){
      const float* __restrict__ cwg = cwf + l*(GG+2*HH);
      float s = 0.f;
      for(int g=0; g<GG; g++) s += attr[t*64 + g]*cwg[g];
      tabS[l*TROWS + r0 + t] = s;
    }
  } else {
    int nb = b - NL*256;
    if(nb < NN/8){
      int f = t & 127, g = t >> 7;
      int n0 = nb*8 + g*4;
      const float* __restrict__ wt = l1t;         // l=0 [k][f]
      float acc[4] = {0.f,0.f,0.f,0.f};
      for(int k=0;k<HH;k++){
        float wv = wt[k*NF + f];
        #pragma unroll
        for(int i=0;i<4;i++) acc[i] += h[(n0+i)*HH + k]*wv;
      }
      #pragma unroll
      for(int i=0;i<4;i++) xfb0[(n0+i)*NF + f] = f2us(acc[i]);
    } else {
      int lane = t & 63;
      int n = (nb - NN/8)*4 + (t >> 6);
      const float* __restrict__ cw = cwf;         // l=0
      float h0 = h[n*HH + lane], h1 = h[n*HH + 64 + lane];
      float ar = h0*cw[GG + lane]      + h1*cw[GG + 64 + lane];
      float ac = h0*cw[GG + HH + lane] + h1*cw[GG + HH + 64 + lane];
      #pragma unroll
      for(int s=32; s>0; s>>=1){
        ar += __shfl_down(ar, s, 64);
        ac += __shfl_down(ac, s, 64);
      }
      if(lane == 0){ dr0[n] = ar; pc40[n*4+3] = ac; }
    }
  }
}

// ---------- per-layer fused kernel, interleaved block types ----------
// b%3==0 -> update unit b/3 (16 nodes): nearest-table gather (unroll 8) ->
// LDS -> MFMA GEMM1/2/3 + dots. Else coordagg unit (8 nodes, pc4 loads).
// Parity ping-pong: reads xfR/drR/pc4R (l), writes xfW/drW/pc4W (l+1).
__global__ void k_layer(const int* __restrict__ col_start, const int* __restrict__ row_s,
                        const float* __restrict__ wEs, const u32* __restrict__ xfR,
                        u16* __restrict__ xfW,
                        const u16* __restrict__ tabB, const int* __restrict__ wmaxi,
                        int l,
                        const u16* __restrict__ l2b, const float* __restrict__ l2bf,
                        const u16* __restrict__ lwb, const float* __restrict__ lbf,
                        float* __restrict__ h, const u16* __restrict__ l1b,
                        const float* __restrict__ cwf,
                        const float* __restrict__ drR, float* __restrict__ drW,
                        const int* __restrict__ row_start, const int* __restrict__ rcol_s,
                        const float* __restrict__ rw_s, const float* __restrict__ tabS,
                        const float* __restrict__ cbf,
                        const float* __restrict__ pc4R, float* __restrict__ pc4W,
                        const u32* __restrict__ zraw, void* __restrict__ out){
  __shared__ __align__(16) u16 T[16*136];
  __shared__ __align__(16) u16 T2[16*136];
  int b = blockIdx.x, t = threadIdx.x;
  float invD = (float)(TROWS-1) / __int_as_float(*wmaxi);
  int wave = t >> 6, lane = t & 63;

  if(b % 3 == 0){
    int n0 = (b/3)*16;
    // ---- gather: nearest table, 8-edge unroll, 4 accumulator pairs ----
    {
      const u32* __restrict__ tg32 = (const u32*)(tabB + (size_t)l*TROWS*NF);
      u32* __restrict__ T32 = (u32*)T;
      #pragma unroll
      for(int j=0;j<2;j++){
        int n = n0 + wave*2 + j;
        int p0 = col_start[n], p1 = col_start[n+1];
        float aa[4] = {0.f,0.f,0.f,0.f};
        float bb[4] = {0.f,0.f,0.f,0.f};
        int p = p0;
        for(; p+8 <= p1; p += 8){
          u32 gv[8], xv[8];
          #pragma unroll
          for(int k=0;k<8;k++){
            int r = row_s[p+k];                   // wave-uniform -> s_load
            int i0 = min((int)(wEs[p+k]*invD + 0.5f), TROWS-1);
            gv[k] = tg32[i0*64 + lane];
            xv[k] = xfR[r*64 + lane];
          }
          #pragma unroll
          for(int k=0;k<8;k++){
            aa[k&3] += us2f((u16)xv[k])      * us2f((u16)gv[k]);
            bb[k&3] += us2f((u16)(xv[k]>>16))* us2f((u16)(gv[k]>>16));
          }
        }
        for(; p < p1; p++){
          int r = row_s[p];
          int i0 = min((int)(wEs[p]*invD + 0.5f), TROWS-1);
          u32 g = tg32[i0*64 + lane];
          u32 x = xfR[r*64 + lane];
          aa[0] += us2f((u16)x)      * us2f((u16)g);
          bb[0] += us2f((u16)(x>>16))* us2f((u16)(g>>16));
        }
        float av = (aa[0]+aa[1])+(aa[2]+aa[3]);
        float bv = (bb[0]+bb[1])+(bb[2]+bb[3]);
        T32[(wave*2+j)*68 + lane] = (u32)f2us(av) | ((u32)f2us(bv) << 16);
      }
    }
    __syncthreads();
    int m16 = lane & 15, quad = lane >> 4;
    int fcol = wave*16 + m16;
    f32x4 acc;
    // ---- GEMM1: sg = ssp(agg @ lin2^T + b) ----
    {
      bf16x8 aA[4];
      #pragma unroll
      for(int ks=0; ks<4; ks++)
        aA[ks] = *(const bf16x8*)&T[m16*136 + ks*32 + quad*8];
      const u16* __restrict__ wA = l2b + l*HH*NF;
      float bv = l2bf[l*HH + fcol];
      acc = (f32x4){bv,bv,bv,bv};
      #pragma unroll
      for(int ks=0; ks<4; ks++){
        bf16x8 bbv = *(const bf16x8*)&wA[fcol*NF + ks*32 + quad*8];
        acc = __builtin_amdgcn_mfma_f32_16x16x32_bf16(aA[ks], bbv, acc, 0,0,0);
      }
      #pragma unroll
      for(int r=0;r<4;r++)
        T2[(quad*4+r)*136 + fcol] = f2us(sspf(acc[r]));
    }
    __syncthreads();
    // ---- GEMM2: hv = h + sg @ lin^T + b ----
    float hv[4];
    int bf = (l == NL-1) ? detect_bf(zraw) : 0;
    {
      bf16x8 aS[4];
      #pragma unroll
      for(int ks=0; ks<4; ks++)
        aS[ks] = *(const bf16x8*)&T2[m16*136 + ks*32 + quad*8];
      const u16* __restrict__ wB = lwb + l*HH*HH;
      float bv = lbf[l*HH + fcol];
      acc = (f32x4){bv,bv,bv,bv};
      #pragma unroll
      for(int ks=0; ks<4; ks++){
        bf16x8 bbv = *(const bf16x8*)&wB[fcol*HH + ks*32 + quad*8];
        acc = __builtin_amdgcn_mfma_f32_16x16x32_bf16(aS[ks], bbv, acc, 0,0,0);
      }
      #pragma unroll
      for(int r=0;r<4;r++)
        hv[r] = h[(n0+quad*4+r)*HH + fcol] + acc[r];
    }
    if(l == NL-1){
      #pragma unroll
      for(int r=0;r<4;r++){
        int n = n0 + quad*4 + r;
        if(bf) ((u16*)out)[NN*3 + n*HH + fcol] = f2us(hv[r]);
        else   ((float*)out)[NN*3 + n*HH + fcol] = hv[r];
      }
      return;
    }
    #pragma unroll
    for(int r=0;r<4;r++){
      int n = n0 + quad*4 + r;
      h[n*HH + fcol] = hv[r];
      T[(quad*4+r)*136 + fcol] = f2us(hv[r]);
    }
    __syncthreads();
    // ---- GEMM3: xf(l+1) = h_new @ lin1^T ----
    {
      bf16x8 aH[4];
      #pragma unroll
      for(int ks=0; ks<4; ks++)
        aH[ks] = *(const bf16x8*)&T[m16*136 + ks*32 + quad*8];
      const u16* __restrict__ wC = l1b + (l+1)*NF*HH;
      acc = (f32x4){0.f,0.f,0.f,0.f};
      #pragma unroll
      for(int ks=0; ks<4; ks++){
        bf16x8 bbv = *(const bf16x8*)&wC[fcol*HH + ks*32 + quad*8];
        acc = __builtin_amdgcn_mfma_f32_16x16x32_bf16(aH[ks], bbv, acc, 0,0,0);
      }
      #pragma unroll
      for(int r=0;r<4;r++)
        xfW[(n0+quad*4+r)*NF + fcol] = f2us(acc[r]);
    }
    // ---- coord dots(l+1) from h_new (32 threads/node) ----
    {
      const float* __restrict__ cw = cwf + (l+1)*(GG + 2*HH);
      int j = t >> 5, l32 = t & 31;
      float ar = 0.f, ac = 0.f;
      #pragma unroll
      for(int i=0;i<4;i++){
        float hvv = us2f(T[j*136 + l32 + 32*i]);
        ar += hvv*cw[GG + l32 + 32*i];
        ac += hvv*cw[GG + HH + l32 + 32*i];
      }
      #pragma unroll
      for(int s=16; s>0; s>>=1){
        ar += __shfl_down(ar, s, 32);
        ac += __shfl_down(ac, s, 32);
      }
      if(l32 == 0){ drW[n0+j] = ar; pc4W[(n0+j)*4+3] = ac; }
    }
  } else {
    // ---- coordagg: 8 nodes/unit (wave per node), 16B pc4 neighbor loads ----
    int u = b - b/3 - 1;                          // 0..NN/8-1
    int bf = (l == NL-1) ? detect_bf(zraw) : 0;
    int n = u*8 + wave;
    const float* __restrict__ ts = tabS + l*TROWS;
    float cb = cbf[l] + drR[n];
    int p0 = row_start[n], p1 = row_start[n+1];
    float4 pn = *(const float4*)&pc4R[n*4];
    float sx=0.f, sy=0.f, sz=0.f;
    for(int p = p0 + lane; p < p1; p += 64){
      int c = rcol_s[p];
      int i0 = min((int)(rw_s[p]*invD + 0.5f), TROWS-1);
      float4 pcv = *(const float4*)&pc4R[c*4];
      float a = cb + pcv.w + ts[i0];
      sx += (pn.x - pcv.x)*a;
      sy += (pn.y - pcv.y)*a;
      sz += (pn.z - pcv.z)*a;
    }
    #pragma unroll
    for(int s=32; s>0; s>>=1){
      sx += __shfl_down(sx, s, 64);
      sy += __shfl_down(sy, s, 64);
      sz += __shfl_down(sz, s, 64);
    }
    if(lane == 0){
      int cnt = p1 - p0;
      float inv = (cnt > 0) ? 1.f/(float)cnt : 0.f;
      float ox = pn.x + sx*inv, oy = pn.y + sy*inv, oz = pn.z + sz*inv;
      if(l == NL-1){
        if(bf){
          u16* o = (u16*)out;
          o[n*3+0] = f2us(ox); o[n*3+1] = f2us(oy); o[n*3+2] = f2us(oz);
        } else {
          float* o = (float*)out;
          o[n*3+0] = ox; o[n*3+1] = oy; o[n*3+2] = oz;
        }
      } else {
        pc4W[n*4+0] = ox; pc4W[n*4+1] = oy; pc4W[n*4+2] = oz;
      }
    }
  }
}

extern "C" void kernel_launch(void* const* d_in, const int* in_sizes, int n_in,
                              void* d_out, int out_size, void* d_ws, size_t ws_size,
                              hipStream_t stream){
  const u32*  z      = (const u32*)d_in[0];
  const void* pos_in = d_in[1];
  const int*  ei_raw = (const int*)d_in[2];
  const void* mlp1_w = d_in[3];
  const void* mlp1_b = d_in[4];
  const void* mlp2_w = d_in[5];
  const void* mlp2_b = d_in[6];
  const void* lin1_w = d_in[7];
  const void* lin2_w = d_in[8];
  const void* lin2_b = d_in[9];
  const void* lin_w  = d_in[10];
  const void* lin_b  = d_in[11];
  const void* coord_w= d_in[12];
  const void* coord_b= d_in[13];

  float* W = (float*)d_ws;
  float* h    = W; W += NN*HH;
  float* pc40 = W; W += NN*4;
  float* pc41 = W; W += NN*4;
  float* dr0  = W; W += NN;
  float* dr1  = W; W += NN;
  float* wE   = W; W += EE;
  float* wEs  = W; W += EE;
  float* rw_s = W; W += EE;
  float* b1f  = W; W += NL*NF;
  float* b2v  = W; W += NL*NF;
  float* w1t  = W; W += NL*GG*NF;
  float* w2t  = W; W += NL*NF*NF;
  float* l1t  = W; W += NL*NF*HH;
  float* l2bf = W; W += NL*HH;
  float* lbf  = W; W += NL*HH;
  float* cwf  = W; W += NL*(GG+2*HH);
  float* cbf  = W; W += NL;
  W = (float*)(((uintptr_t)W + 63) & ~(uintptr_t)63);
  u16*  tabB = (u16*)W; W += (size_t)NL*TROWS*NF/2;   // bf16 nearest table
  float* tabS = W; W += NL*TROWS;
  u16* l1b  = (u16*)W; W += (NL*NF*NF)/2;
  u16* l2b  = (u16*)W; W += (NL*NF*NF)/2;
  u16* lwb  = (u16*)W; W += (NL*NF*NF)/2;
  u16* xfb0 = (u16*)W; W += (NN*NF)/2;
  u16* xfb1 = (u16*)W; W += (NN*NF)/2;
  u16* partR16 = (u16*)W; W += (size_t)NB*NN/2;
  u16* partC16 = (u16*)W; W += (size_t)NB*NN/2;
  int* degR      = (int*)W; W += NN;
  int* degC      = (int*)W; W += NN;
  int* col_start = (int*)W; W += NN+1;
  int* row_start = (int*)W; W += NN+1;
  int* row_s     = (int*)W; W += EE;
  int* rcol_s    = (int*)W; W += EE;
  int* eiN       = (int*)W; W += 2*EE;
  int* wmaxi     = (int*)W; W += 1;

  k_prep<<<NN*HH/256 + NL*NF*NF/256, 256, 0, stream>>>(
      z, pos_in, mlp1_w, mlp1_b, mlp2_w, mlp2_b, lin1_w, lin2_w, lin2_b,
      lin_w, lin_b, coord_w, coord_b,
      h, pc40, wmaxi,
      b1f, b2v, w1t, w2t, l1t, l1b, l2b, l2bf, lwb, lbf, cwf, cbf);
  k_count<<<NB, 256, 0, stream>>>(ei_raw, pc40, eiN, wE,
                                  (u32*)partR16, (u32*)partC16, wmaxi);
  k_sumpref<<<(NN+255)/256, 256, 0, stream>>>(partR16, partC16, degR, degC);
  k_scan2<<<1, 1024, 0, stream>>>(degC, degR, col_start, row_start);
  k_fill<<<NB, 256, 0, stream>>>(eiN, wE, col_start, row_start, partR16, partC16,
                                 row_s, wEs, rcol_s, rw_s);
  k_tabnode<<<NL*256 + NN/8 + NN/4, 256, 0, stream>>>(
      w1t, b1f, w2t, b2v, cwf, wmaxi, tabB, tabS,
      h, l1t, xfb0, dr0, pc40);

  for(int l=0; l<NL; l++){
    int par = l & 1;
    const u32* xfR = (const u32*)(par ? xfb1 : xfb0);
    u16* xfW = par ? xfb0 : xfb1;
    const float* drR = par ? dr1 : dr0;   float* drW = par ? dr0 : dr1;
    const float* p4R = par ? pc41 : pc40; float* p4W = par ? pc40 : pc41;
    k_layer<<<3*(NN/16), 512, 0, stream>>>(      // 1875 = 625 update + 1250 coord
        col_start, row_s, wEs, xfR, xfW, tabB, wmaxi, l,
        l2b, l2bf, lwb, lbf, h, l1b, cwf,
        drR, drW,
        row_start, rcol_s, rw_s, tabS, cbf, p4R, p4W, z, d_out);
  }
}

// Round 16
// 409.817 us; speedup vs baseline: 1.0433x; 1.0433x over previous
//
#include <hip/hip_runtime.h>

// SchNet on MI355X — round 16: revert TROWS to 2048 (round 15's 4096 doubled
// k_tabnode to 54 us for error margin we don't need; nearest-lookup error at
// 2048 is ~0.004 << 0.5 absmax), fold k_sumpref into k_tabnode's grid.
// k_layer structure (nearest table, unroll-8, interleaved blocks, pc4) kept.

#define NN 10000
#define EE 320000
#define HH 128
#define GG 50
#define NF 128
#define NL 6
#define TROWS 2048
#define NB 128          // histogram blocks; EE/NB = 2500 edges each (fits u16)

typedef unsigned short u16;
typedef unsigned int u32;
typedef short bf16x8 __attribute__((ext_vector_type(8)));
typedef float f32x4  __attribute__((ext_vector_type(4)));

__device__ __forceinline__ float us2f(u16 u){
  union { float f; u32 i; } v; v.i = ((u32)u) << 16; return v.f;
}
__device__ __forceinline__ u16 f2us(float x){
  union { float f; u32 i; } v; v.f = x;
  u32 r = v.i + 0x7fffu + ((v.i >> 16) & 1u);   // RNE
  return (u16)(r >> 16);
}
__device__ __forceinline__ float ldin(const void* p, int i, int bf){
  return bf ? us2f(((const u16*)p)[i]) : ((const float*)p)[i];
}
__device__ __forceinline__ float sspf(float x){
  return fmaxf(x, 0.f) + __logf(1.f + __expf(-fabsf(x))) - 0.6931472f;
}
__device__ __forceinline__ int detect_bf(const u32* __restrict__ zraw){
  int lane = threadIdx.x & 63;
  int c = 0;
  #pragma unroll
  for(int j=0;j<4;j++){
    u32 w = zraw[lane*4+j];
    u32 hb = (w >> 8) & 0x7F;
    c += (hb >= 0x38 && hb <= 0x41) ? 1 : 0;
  }
  return __popcll(__ballot(c >= 2)) >= 32;
}
__device__ __forceinline__ int detect_i64(const int* __restrict__ ei_raw){
  int lane = threadIdx.x & 63;
  int c = 0;
  #pragma unroll
  for(int j=0;j<4;j++) c += (ei_raw[2*(lane*4+j)+1] == 0) ? 1 : 0;
  return __popcll(__ballot(c >= 3)) >= 32;
}

// ---------- K1: fused init + weight prep ----------
__global__ void k_prep(const u32* __restrict__ zraw, const void* __restrict__ pos_in,
    const void* __restrict__ mlp1_w, const void* __restrict__ mlp1_b,
    const void* __restrict__ mlp2_w, const void* __restrict__ mlp2_b,
    const void* __restrict__ lin1_w, const void* __restrict__ lin2_w,
    const void* __restrict__ lin2_b, const void* __restrict__ lin_w,
    const void* __restrict__ lin_b,  const void* __restrict__ coord_w,
    const void* __restrict__ coord_b,
    float* __restrict__ h, float* __restrict__ pc40, int* __restrict__ wmaxi,
    float* __restrict__ b1f, float* __restrict__ b2v,
    float* __restrict__ w1t, float* __restrict__ w2t,
    float* __restrict__ l1t, u16* __restrict__ l1b, u16* __restrict__ l2b,
    float* __restrict__ l2bf, u16* __restrict__ lwb,
    float* __restrict__ lbf, float* __restrict__ cwf, float* __restrict__ cbf)
{
  int bf = detect_bf(zraw);
  int b = blockIdx.x;
  if(b < NN*HH/256){
    int i = b*256 + threadIdx.x;
    h[i] = ldin(zraw, i, bf);
    if(i < NN*3){
      int n = i/3, comp = i%3;
      pc40[n*4 + comp] = ldin(pos_in, i, bf);
    }
    if(i == 0) *wmaxi = 0;
  } else {
    int i = (b - NN*HH/256)*256 + threadIdx.x;    // < NL*NF*NF
    if(i < NL*NF){
      b1f[i]  = ldin(mlp1_b, i, bf);
      b2v[i]  = ldin(mlp2_b, i, bf);
      l2bf[i] = ldin(lin2_b, i, bf);
      lbf[i]  = ldin(lin_b,  i, bf);
    }
    if(i < NL*GG*NF){                             // w1t[l][g][f]
      int l = i/(GG*NF), rem = i%(GG*NF);
      int g = rem/NF, f = rem%NF;
      w1t[i] = ldin(mlp1_w, (l*NF + f)*GG + g, bf);
    }
    if(i < NL*NF*NF){
      int l = i/(NF*NF), rem = i%(NF*NF);
      int k = rem/NF, f = rem%NF;
      w2t[i] = ldin(mlp2_w, l*NF*NF + f*NF + k, bf);
      l1t[i] = ldin(lin1_w, l*NF*HH + f*HH + k, bf);
      l1b[i] = f2us(ldin(lin1_w, i, bf));         // row-major bf16 (MFMA B)
      l2b[i] = f2us(ldin(lin2_w, i, bf));
      lwb[i] = f2us(ldin(lin_w,  i, bf));
    }
    if(i < NL*(GG+2*HH)) cwf[i] = ldin(coord_w, i, bf);
    if(i < NL) cbf[i] = ldin(coord_b, i, bf);
  }
}

// ---------- K2: decode ei, distances (pc4 float4), LDS histograms ----------
__global__ void k_count(const int* __restrict__ ei_raw, const float* __restrict__ pc4,
                        int* __restrict__ eiN, float* __restrict__ wE,
                        u32* __restrict__ partR32, u32* __restrict__ partC32,
                        int* __restrict__ wmaxi){
  __shared__ u32 hr[NN/2];
  __shared__ u32 hc[NN/2];
  int is64 = detect_i64(ei_raw);
  int b = blockIdx.x, tid = threadIdx.x;          // grid: NB x 256
  for(int i=tid; i<NN/2; i+=256){ hr[i]=0; hc[i]=0; }
  __syncthreads();
  int e0 = b*(EE/NB), e1 = e0 + EE/NB;
  float wm = 0.f;
  for(int e = e0 + tid; e < e1; e += 256){
    int r = is64 ? ei_raw[2*e] : ei_raw[e];
    int c = is64 ? ei_raw[2*(EE+e)] : ei_raw[EE+e];
    eiN[e] = r; eiN[EE+e] = c;
    float4 pr = *(const float4*)&pc4[r*4];
    float4 pcv = *(const float4*)&pc4[c*4];
    float dx = pr.x-pcv.x, dy = pr.y-pcv.y, dz = pr.z-pcv.z;
    float w = sqrtf(dx*dx + dy*dy + dz*dz);
    wE[e] = w;
    wm = fmaxf(wm, w);
    atomicAdd(&hr[r>>1], (r&1) ? 0x10000u : 1u);
    atomicAdd(&hc[c>>1], (c&1) ? 0x10000u : 1u);
  }
  #pragma unroll
  for(int s=32; s>0; s>>=1) wm = fmaxf(wm, __shfl_down(wm, s, 64));
  if((tid & 63) == 0) atomicMax(wmaxi, __float_as_int(wm));
  __syncthreads();
  for(int i=tid; i<NN/2; i+=256){
    partR32[(size_t)b*(NN/2) + i] = hr[i];
    partC32[(size_t)b*(NN/2) + i] = hc[i];
  }
}

// ---------- K4: merged dual exclusive scan ----------
__global__ void k_scan2(const int* __restrict__ col_deg, const int* __restrict__ deg_row,
                        int* __restrict__ col_start, int* __restrict__ row_start){
  __shared__ int pc[1024];
  __shared__ int pr[1024];
  int tid = threadIdx.x;
  const int CH = (NN + 1023)/1024;
  int base = tid*CH;
  int sc = 0, sr = 0;
  for(int i=0;i<CH;i++){
    int idx = base+i;
    if(idx<NN){ sc += col_deg[idx]; sr += deg_row[idx]; }
  }
  pc[tid] = sc; pr[tid] = sr;
  __syncthreads();
  for(int off=1; off<1024; off<<=1){
    int vc = (tid>=off) ? pc[tid-off] : 0;
    int vr = (tid>=off) ? pr[tid-off] : 0;
    __syncthreads();
    pc[tid] += vc; pr[tid] += vr;
    __syncthreads();
  }
  int runc = (tid==0) ? 0 : pc[tid-1];
  int runr = (tid==0) ? 0 : pr[tid-1];
  for(int i=0;i<CH;i++){
    int idx = base+i;
    if(idx<NN){
      col_start[idx]=runc; runc += col_deg[idx];
      row_start[idx]=runr; runr += deg_row[idx];
    }
  }
  if(tid==1023){ col_start[NN] = runc; row_start[NN] = runr; }
}

// ---------- K5a: CSR fill via LDS rank histograms ----------
__global__ void k_fill(const int* __restrict__ eiN, const float* __restrict__ wE,
                       const int* __restrict__ col_start, const int* __restrict__ row_start,
                       const u16* __restrict__ partR16, const u16* __restrict__ partC16,
                       int* __restrict__ row_s, float* __restrict__ wEs,
                       int* __restrict__ rcol_s, float* __restrict__ rw_s){
  __shared__ u32 hr[NN/2];
  __shared__ u32 hc[NN/2];
  int b = blockIdx.x, t = threadIdx.x;
  for(int i=t; i<NN/2; i+=256){ hr[i]=0; hc[i]=0; }
  __syncthreads();
  int e0 = b*(EE/NB), e1 = e0 + EE/NB;
  for(int e = e0 + t; e < e1; e += 256){
    int r = eiN[e], c = eiN[EE+e];
    float w = wE[e];
    u32 oldc = atomicAdd(&hc[c>>1], (c&1) ? 0x10000u : 1u);
    u32 rkc = (c&1) ? (oldc >> 16) : (oldc & 0xFFFFu);
    int p = col_start[c] + (int)partC16[(size_t)b*NN + c] + (int)rkc;
    row_s[p] = r; wEs[p] = w;
    u32 oldr = atomicAdd(&hr[r>>1], (r&1) ? 0x10000u : 1u);
    u32 rkr = (r&1) ? (oldr >> 16) : (oldr & 0xFFFFu);
    int p2 = row_start[r] + (int)partR16[(size_t)b*NN + r] + (int)rkr;
    rcol_s[p2] = c; rw_s[p2] = w;
  }
}

// ---------- K5b: table build + layer-0 node + sumpref (fused grid) ----------
// blocks [0, NL*128)            : table (16 rows each, bf16 nearest table)
// blocks [NL*128, +NN/8)        : layer-0 xf
// blocks [.., +NN/4)            : layer-0 dots
// blocks [.., +40)              : sumpref (independent of table/node)
__global__ void k_tabnode(const float* __restrict__ w1t, const float* __restrict__ b1f,
                          const float* __restrict__ w2t, const float* __restrict__ b2v,
                          const float* __restrict__ cwf, const int* __restrict__ wmaxi,
                          u16* __restrict__ tabB, float* __restrict__ tabS,
                          const float* __restrict__ h, const float* __restrict__ l1t,
                          u16* __restrict__ xfb0, float* __restrict__ dr0,
                          float* __restrict__ pc40,
                          u16* __restrict__ partR16, u16* __restrict__ partC16,
                          int* __restrict__ degR, int* __restrict__ degC){
  __shared__ float attr[16*64];                   // 4 KB
  __shared__ float tls[128*17];                   // 8.5 KB
  int b = blockIdx.x, t = threadIdx.x;
  if(b < NL*128){
    int l = b >> 7;
    int r0 = (b & 127)*16;
    int f = t & 127, half = t >> 7;
    float delta = __int_as_float(*wmaxi) / (float)(TROWS-1);
    for(int idx=t; idx<16*64; idx+=256){
      int r = idx >> 6, g = idx & 63;
      float w = (float)(r0 + r)*delta;
      float d = w - (float)g*(10.f/49.f);
      attr[idx] = (g < GG) ? __expf(-12.005f*d*d) : 0.f;
    }
    __syncthreads();
    const float* __restrict__ w1 = w1t + l*GG*NF;
    float b1 = b1f[l*NF + f];
    float a1[8];
    #pragma unroll
    for(int r=0;r<8;r++) a1[r] = b1;
    for(int g=0; g<GG; g++){
      float wv = w1[g*NF + f];
      #pragma unroll
      for(int r=0;r<8;r++) a1[r] += attr[(half*8 + r)*64 + g]*wv;
    }
    #pragma unroll
    for(int r=0;r<8;r++) tls[f*17 + half*8 + r] = sspf(a1[r]);
    __syncthreads();
    const float* __restrict__ w2 = w2t + l*NF*NF;
    float b2 = b2v[l*NF + f];
    float a2[8];
    #pragma unroll
    for(int r=0;r<8;r++) a2[r] = b2;
    for(int k=0;k<NF;k++){
      float wv = w2[k*NF + f];
      #pragma unroll
      for(int r=0;r<8;r++) a2[r] += tls[k*17 + half*8 + r]*wv;
    }
    #pragma unroll
    for(int r=0;r<8;r++){
      int row = r0 + half*8 + r;
      float w = (float)row*delta;
      float C = 0.5f*(cosf(w*0.3141592653589793f) + 1.f);
      tabB[((size_t)l*TROWS + row)*NF + f] = f2us(a2[r]*C);
    }
    if(t < 16){
      const float* __restrict__ cwg = cwf + l*(GG+2*HH);
      float s = 0.f;
      for(int g=0; g<GG; g++) s += attr[t*64 + g]*cwg[g];
      tabS[l*TROWS + r0 + t] = s;
    }
  } else if(b < NL*128 + NN/8 + NN/4){
    int nb = b - NL*128;
    if(nb < NN/8){
      int f = t & 127, g = t >> 7;
      int n0 = nb*8 + g*4;
      const float* __restrict__ wt = l1t;         // l=0 [k][f]
      float acc[4] = {0.f,0.f,0.f,0.f};
      for(int k=0;k<HH;k++){
        float wv = wt[k*NF + f];
        #pragma unroll
        for(int i=0;i<4;i++) acc[i] += h[(n0+i)*HH + k]*wv;
      }
      #pragma unroll
      for(int i=0;i<4;i++) xfb0[(n0+i)*NF + f] = f2us(acc[i]);
    } else {
      int lane = t & 63;
      int n = (nb - NN/8)*4 + (t >> 6);
      const float* __restrict__ cw = cwf;         // l=0
      float h0 = h[n*HH + lane], h1 = h[n*HH + 64 + lane];
      float ar = h0*cw[GG + lane]      + h1*cw[GG + 64 + lane];
      float ac = h0*cw[GG + HH + lane] + h1*cw[GG + HH + 64 + lane];
      #pragma unroll
      for(int s=32; s>0; s>>=1){
        ar += __shfl_down(ar, s, 64);
        ac += __shfl_down(ac, s, 64);
      }
      if(lane == 0){ dr0[n] = ar; pc40[n*4+3] = ac; }
    }
  } else {
    // ---- sumpref: u16 partials -> exclusive block-prefixes + totals ----
    int n = (b - (NL*128 + NN/8 + NN/4))*256 + t;
    if(n >= NN) return;
    u32 rr = 0, rc = 0;
    for(int b0=0; b0<NB; b0+=8){
      u32 vr[8], vc[8];
      #pragma unroll
      for(int j=0;j<8;j++){
        vr[j] = partR16[(size_t)(b0+j)*NN + n];
        vc[j] = partC16[(size_t)(b0+j)*NN + n];
      }
      #pragma unroll
      for(int j=0;j<8;j++){
        partR16[(size_t)(b0+j)*NN + n] = (u16)rr; rr += vr[j];
        partC16[(size_t)(b0+j)*NN + n] = (u16)rc; rc += vc[j];
      }
    }
    degR[n] = (int)rr; degC[n] = (int)rc;
  }
}

// ---------- per-layer fused kernel, interleaved block types ----------
// b%3==0 -> update unit b/3 (16 nodes): nearest-table gather (unroll 8) ->
// LDS -> MFMA GEMM1/2/3 + dots. Else coordagg unit (8 nodes, pc4 loads).
// Parity ping-pong: reads xfR/drR/pc4R (l), writes xfW/drW/pc4W (l+1).
__global__ void k_layer(const int* __restrict__ col_start, const int* __restrict__ row_s,
                        const float* __restrict__ wEs, const u32* __restrict__ xfR,
                        u16* __restrict__ xfW,
                        const u16* __restrict__ tabB, const int* __restrict__ wmaxi,
                        int l,
                        const u16* __restrict__ l2b, const float* __restrict__ l2bf,
                        const u16* __restrict__ lwb, const float* __restrict__ lbf,
                        float* __restrict__ h, const u16* __restrict__ l1b,
                        const float* __restrict__ cwf,
                        const float* __restrict__ drR, float* __restrict__ drW,
                        const int* __restrict__ row_start, const int* __restrict__ rcol_s,
                        const float* __restrict__ rw_s, const float* __restrict__ tabS,
                        const float* __restrict__ cbf,
                        const float* __restrict__ pc4R, float* __restrict__ pc4W,
                        const u32* __restrict__ zraw, void* __restrict__ out){
  __shared__ __align__(16) u16 T[16*136];
  __shared__ __align__(16) u16 T2[16*136];
  int b = blockIdx.x, t = threadIdx.x;
  float invD = (float)(TROWS-1) / __int_as_float(*wmaxi);
  int wave = t >> 6, lane = t & 63;

  if(b % 3 == 0){
    int n0 = (b/3)*16;
    // ---- gather: nearest table, 8-edge unroll, 4 accumulator pairs ----
    {
      const u32* __restrict__ tg32 = (const u32*)(tabB + (size_t)l*TROWS*NF);
      u32* __restrict__ T32 = (u32*)T;
      #pragma unroll
      for(int j=0;j<2;j++){
        int n = n0 + wave*2 + j;
        int p0 = col_start[n], p1 = col_start[n+1];
        float aa[4] = {0.f,0.f,0.f,0.f};
        float bb[4] = {0.f,0.f,0.f,0.f};
        int p = p0;
        for(; p+8 <= p1; p += 8){
          u32 gv[8], xv[8];
          #pragma unroll
          for(int k=0;k<8;k++){
            int r = row_s[p+k];                   // wave-uniform -> s_load
            int i0 = min((int)(wEs[p+k]*invD + 0.5f), TROWS-1);
            gv[k] = tg32[i0*64 + lane];
            xv[k] = xfR[r*64 + lane];
          }
          #pragma unroll
          for(int k=0;k<8;k++){
            aa[k&3] += us2f((u16)xv[k])      * us2f((u16)gv[k]);
            bb[k&3] += us2f((u16)(xv[k]>>16))* us2f((u16)(gv[k]>>16));
          }
        }
        for(; p < p1; p++){
          int r = row_s[p];
          int i0 = min((int)(wEs[p]*invD + 0.5f), TROWS-1);
          u32 g = tg32[i0*64 + lane];
          u32 x = xfR[r*64 + lane];
          aa[0] += us2f((u16)x)      * us2f((u16)g);
          bb[0] += us2f((u16)(x>>16))* us2f((u16)(g>>16));
        }
        float av = (aa[0]+aa[1])+(aa[2]+aa[3]);
        float bv = (bb[0]+bb[1])+(bb[2]+bb[3]);
        T32[(wave*2+j)*68 + lane] = (u32)f2us(av) | ((u32)f2us(bv) << 16);
      }
    }
    __syncthreads();
    int m16 = lane & 15, quad = lane >> 4;
    int fcol = wave*16 + m16;
    f32x4 acc;
    // ---- GEMM1: sg = ssp(agg @ lin2^T + b) ----
    {
      bf16x8 aA[4];
      #pragma unroll
      for(int ks=0; ks<4; ks++)
        aA[ks] = *(const bf16x8*)&T[m16*136 + ks*32 + quad*8];
      const u16* __restrict__ wA = l2b + l*HH*NF;
      float bv = l2bf[l*HH + fcol];
      acc = (f32x4){bv,bv,bv,bv};
      #pragma unroll
      for(int ks=0; ks<4; ks++){
        bf16x8 bbv = *(const bf16x8*)&wA[fcol*NF + ks*32 + quad*8];
        acc = __builtin_amdgcn_mfma_f32_16x16x32_bf16(aA[ks], bbv, acc, 0,0,0);
      }
      #pragma unroll
      for(int r=0;r<4;r++)
        T2[(quad*4+r)*136 + fcol] = f2us(sspf(acc[r]));
    }
    __syncthreads();
    // ---- GEMM2: hv = h + sg @ lin^T + b ----
    float hv[4];
    int bf = (l == NL-1) ? detect_bf(zraw) : 0;
    {
      bf16x8 aS[4];
      #pragma unroll
      for(int ks=0; ks<4; ks++)
        aS[ks] = *(const bf16x8*)&T2[m16*136 + ks*32 + quad*8];
      const u16* __restrict__ wB = lwb + l*HH*HH;
      float bv = lbf[l*HH + fcol];
      acc = (f32x4){bv,bv,bv,bv};
      #pragma unroll
      for(int ks=0; ks<4; ks++){
        bf16x8 bbv = *(const bf16x8*)&wB[fcol*HH + ks*32 + quad*8];
        acc = __builtin_amdgcn_mfma_f32_16x16x32_bf16(aS[ks], bbv, acc, 0,0,0);
      }
      #pragma unroll
      for(int r=0;r<4;r++)
        hv[r] = h[(n0+quad*4+r)*HH + fcol] + acc[r];
    }
    if(l == NL-1){
      #pragma unroll
      for(int r=0;r<4;r++){
        int n = n0 + quad*4 + r;
        if(bf) ((u16*)out)[NN*3 + n*HH + fcol] = f2us(hv[r]);
        else   ((float*)out)[NN*3 + n*HH + fcol] = hv[r];
      }
      return;
    }
    #pragma unroll
    for(int r=0;r<4;r++){
      int n = n0 + quad*4 + r;
      h[n*HH + fcol] = hv[r];
      T[(quad*4+r)*136 + fcol] = f2us(hv[r]);
    }
    __syncthreads();
    // ---- GEMM3: xf(l+1) = h_new @ lin1^T ----
    {
      bf16x8 aH[4];
      #pragma unroll
      for(int ks=0; ks<4; ks++)
        aH[ks] = *(const bf16x8*)&T[m16*136 + ks*32 + quad*8];
      const u16* __restrict__ wC = l1b + (l+1)*NF*HH;
      acc = (f32x4){0.f,0.f,0.f,0.f};
      #pragma unroll
      for(int ks=0; ks<4; ks++){
        bf16x8 bbv = *(const bf16x8*)&wC[fcol*HH + ks*32 + quad*8];
        acc = __builtin_amdgcn_mfma_f32_16x16x32_bf16(aH[ks], bbv, acc, 0,0,0);
      }
      #pragma unroll
      for(int r=0;r<4;r++)
        xfW[(n0+quad*4+r)*NF + fcol] = f2us(acc[r]);
    }
    // ---- coord dots(l+1) from h_new (32 threads/node) ----
    {
      const float* __restrict__ cw = cwf + (l+1)*(GG + 2*HH);
      int j = t >> 5, l32 = t & 31;
      float ar = 0.f, ac = 0.f;
      #pragma unroll
      for(int i=0;i<4;i++){
        float hvv = us2f(T[j*136 + l32 + 32*i]);
        ar += hvv*cw[GG + l32 + 32*i];
        ac += hvv*cw[GG + HH + l32 + 32*i];
      }
      #pragma unroll
      for(int s=16; s>0; s>>=1){
        ar += __shfl_down(ar, s, 32);
        ac += __shfl_down(ac, s, 32);
      }
      if(l32 == 0){ drW[n0+j] = ar; pc4W[(n0+j)*4+3] = ac; }
    }
  } else {
    // ---- coordagg: 8 nodes/unit (wave per node), 16B pc4 neighbor loads ----
    int u = b - b/3 - 1;                          // 0..NN/8-1
    int bf = (l == NL-1) ? detect_bf(zraw) : 0;
    int n = u*8 + wave;
    const float* __restrict__ ts = tabS + l*TROWS;
    float cb = cbf[l] + drR[n];
    int p0 = row_start[n], p1 = row_start[n+1];
    float4 pn = *(const float4*)&pc4R[n*4];
    float sx=0.f, sy=0.f, sz=0.f;
    for(int p = p0 + lane; p < p1; p += 64){
      int c = rcol_s[p];
      int i0 = min((int)(rw_s[p]*invD + 0.5f), TROWS-1);
      float4 pcv = *(const float4*)&pc4R[c*4];
      float a = cb + pcv.w + ts[i0];
      sx += (pn.x - pcv.x)*a;
      sy += (pn.y - pcv.y)*a;
      sz += (pn.z - pcv.z)*a;
    }
    #pragma unroll
    for(int s=32; s>0; s>>=1){
      sx += __shfl_down(sx, s, 64);
      sy += __shfl_down(sy, s, 64);
      sz += __shfl_down(sz, s, 64);
    }
    if(lane == 0){
      int cnt = p1 - p0;
      float inv = (cnt > 0) ? 1.f/(float)cnt : 0.f;
      float ox = pn.x + sx*inv, oy = pn.y + sy*inv, oz = pn.z + sz*inv;
      if(l == NL-1){
        if(bf){
          u16* o = (u16*)out;
          o[n*3+0] = f2us(ox); o[n*3+1] = f2us(oy); o[n*3+2] = f2us(oz);
        } else {
          float* o = (float*)out;
          o[n*3+0] = ox; o[n*3+1] = oy; o[n*3+2] = oz;
        }
      } else {
        pc4W[n*4+0] = ox; pc4W[n*4+1] = oy; pc4W[n*4+2] = oz;
      }
    }
  }
}

extern "C" void kernel_launch(void* const* d_in, const int* in_sizes, int n_in,
                              void* d_out, int out_size, void* d_ws, size_t ws_size,
                              hipStream_t stream){
  const u32*  z      = (const u32*)d_in[0];
  const void* pos_in = d_in[1];
  const int*  ei_raw = (const int*)d_in[2];
  const void* mlp1_w = d_in[3];
  const void* mlp1_b = d_in[4];
  const void* mlp2_w = d_in[5];
  const void* mlp2_b = d_in[6];
  const void* lin1_w = d_in[7];
  const void* lin2_w = d_in[8];
  const void* lin2_b = d_in[9];
  const void* lin_w  = d_in[10];
  const void* lin_b  = d_in[11];
  const void* coord_w= d_in[12];
  const void* coord_b= d_in[13];

  float* W = (float*)d_ws;
  float* h    = W; W += NN*HH;
  float* pc40 = W; W += NN*4;
  float* pc41 = W; W += NN*4;
  float* dr0  = W; W += NN;
  float* dr1  = W; W += NN;
  float* wE   = W; W += EE;
  float* wEs  = W; W += EE;
  float* rw_s = W; W += EE;
  float* b1f  = W; W += NL*NF;
  float* b2v  = W; W += NL*NF;
  float* w1t  = W; W += NL*GG*NF;
  float* w2t  = W; W += NL*NF*NF;
  float* l1t  = W; W += NL*NF*HH;
  float* l2bf = W; W += NL*HH;
  float* lbf  = W; W += NL*HH;
  float* cwf  = W; W += NL*(GG+2*HH);
  float* cbf  = W; W += NL;
  W = (float*)(((uintptr_t)W + 63) & ~(uintptr_t)63);
  u16*  tabB = (u16*)W; W += (size_t)NL*TROWS*NF/2;   // bf16 nearest table
  float* tabS = W; W += NL*TROWS;
  u16* l1b  = (u16*)W; W += (NL*NF*NF)/2;
  u16* l2b  = (u16*)W; W += (NL*NF*NF)/2;
  u16* lwb  = (u16*)W; W += (NL*NF*NF)/2;
  u16* xfb0 = (u16*)W; W += (NN*NF)/2;
  u16* xfb1 = (u16*)W; W += (NN*NF)/2;
  u16* partR16 = (u16*)W; W += (size_t)NB*NN/2;
  u16* partC16 = (u16*)W; W += (size_t)NB*NN/2;
  int* degR      = (int*)W; W += NN;
  int* degC      = (int*)W; W += NN;
  int* col_start = (int*)W; W += NN+1;
  int* row_start = (int*)W; W += NN+1;
  int* row_s     = (int*)W; W += EE;
  int* rcol_s    = (int*)W; W += EE;
  int* eiN       = (int*)W; W += 2*EE;
  int* wmaxi     = (int*)W; W += 1;

  k_prep<<<NN*HH/256 + NL*NF*NF/256, 256, 0, stream>>>(
      z, pos_in, mlp1_w, mlp1_b, mlp2_w, mlp2_b, lin1_w, lin2_w, lin2_b,
      lin_w, lin_b, coord_w, coord_b,
      h, pc40, wmaxi,
      b1f, b2v, w1t, w2t, l1t, l1b, l2b, l2bf, lwb, lbf, cwf, cbf);
  k_count<<<NB, 256, 0, stream>>>(ei_raw, pc40, eiN, wE,
                                  (u32*)partR16, (u32*)partC16, wmaxi);
  k_tabnode<<<NL*128 + NN/8 + NN/4 + (NN+255)/256, 256, 0, stream>>>(
      w1t, b1f, w2t, b2v, cwf, wmaxi, tabB, tabS,
      h, l1t, xfb0, dr0, pc40,
      partR16, partC16, degR, degC);
  k_scan2<<<1, 1024, 0, stream>>>(degC, degR, col_start, row_start);
  k_fill<<<NB, 256, 0, stream>>>(eiN, wE, col_start, row_start, partR16, partC16,
                                 row_s, wEs, rcol_s, rw_s);

  for(int l=0; l<NL; l++){
    int par = l & 1;
    const u32* xfR = (const u32*)(par ? xfb1 : xfb0);
    u16* xfW = par ? xfb0 : xfb1;
    const float* drR = par ? dr1 : dr0;   float* drW = par ? dr0 : dr1;
    const float* p4R = par ? pc41 : pc40; float* p4W = par ? pc40 : pc41;
    k_layer<<<3*(NN/16), 512, 0, stream>>>(      // 1875 = 625 update + 1250 coord
        col_start, row_s, wEs, xfR, xfW, tabB, wmaxi, l,
        l2b, l2bf, lwb, lbf, h, l1b, cwf,
        drR, drW,
        row_start, rcol_s, rw_s, tabS, cbf, p4R, p4W, z, d_out);
  }
}